// Round 2
// baseline (1696.259 us; speedup 1.0000x reference)
//
#include <hip/hip_runtime.h>
#include <hip/hip_bf16.h>
#include <stdint.h>

#define N_USER 100000
#define N_ITEM 50000
#define NTOT   150000
#define NEDGE  1200000
#define D      64
#define OUTD   256
#define NEG    0.01f
#define NBLK   586   // ceil(150000/256)

// Build E = concat(user_emb, item_emb) and write output chunk 0 (raw emb, fp32)
__global__ void k_init(const float* __restrict__ ue, const float* __restrict__ ie,
                       float* __restrict__ E, float* __restrict__ out) {
    int t = blockIdx.x * blockDim.x + threadIdx.x;
    if (t >= NTOT * 16) return;
    int r = t >> 4, q = t & 15;
    const float* src = (r < N_USER) ? (ue + (size_t)r * D)
                                    : (ie + (size_t)(r - N_USER) * D);
    float4 v = *(const float4*)(src + q * 4);
    *(float4*)(E + (size_t)r * D + q * 4) = v;
    *(float4*)(out + (size_t)r * OUTD + q * 4) = v;
}

__global__ void k_hist(const int* __restrict__ row, int* __restrict__ cnt) {
    int e = blockIdx.x * blockDim.x + threadIdx.x;
    if (e < NEDGE) atomicAdd(&cnt[row[e]], 1);
}

// Phase A: per-block (256) partial sums of counts
__global__ void k_scan_a(const int* __restrict__ cnt, int* __restrict__ part) {
    __shared__ int s[4];
    int i = blockIdx.x * 256 + threadIdx.x;
    int v = (i < NTOT) ? cnt[i] : 0;
    for (int off = 32; off; off >>= 1) v += __shfl_down(v, off, 64);
    if ((threadIdx.x & 63) == 0) s[threadIdx.x >> 6] = v;
    __syncthreads();
    if (threadIdx.x == 0) part[blockIdx.x] = s[0] + s[1] + s[2] + s[3];
}

// Phase B: single-block exclusive scan of NBLK partials
__global__ void k_scan_b(int* __restrict__ part) {
    __shared__ int s[1024];
    int t = threadIdx.x;
    int v = (t < NBLK) ? part[t] : 0;
    s[t] = v;
    __syncthreads();
    for (int off = 1; off < 1024; off <<= 1) {
        int x = (t >= off) ? s[t - off] : 0;
        __syncthreads();
        s[t] += x;
        __syncthreads();
    }
    if (t < NBLK) part[t] = s[t] - v;  // exclusive
}

// Phase C: in-block exclusive scan + block base -> offsets and cursor copy
__global__ void k_scan_c(const int* __restrict__ cnt, const int* __restrict__ part,
                         int* __restrict__ offs, int* __restrict__ cur) {
    __shared__ int ws[4];
    int i = blockIdx.x * 256 + threadIdx.x;
    int v = (i < NTOT) ? cnt[i] : 0;
    int lane = threadIdx.x & 63, w = threadIdx.x >> 6;
    int x = v;
    for (int o = 1; o < 64; o <<= 1) {
        int y = __shfl_up(x, o, 64);
        if (lane >= o) x += y;
    }
    if (lane == 63) ws[w] = x;
    __syncthreads();
    int base = part[blockIdx.x];
    for (int k = 0; k < w; k++) base += ws[k];
    int excl = base + x - v;
    if (i < NTOT) { offs[i] = excl; cur[i] = excl; }
    if (i == 0) offs[NTOT] = NEDGE;
}

__global__ void k_scatter(const int* __restrict__ row, const int* __restrict__ col,
                          const float* __restrict__ val, int* __restrict__ cur,
                          int* __restrict__ ccol, float* __restrict__ cval) {
    int e = blockIdx.x * blockDim.x + threadIdx.x;
    if (e >= NEDGE) return;
    int r = row[e];
    int p = atomicAdd(&cur[r], 1);
    ccol[p] = col[e];
    cval[p] = val[e];
}

// front = (H + I) @ E : wave per row, lane per dim
__global__ void k_spmm(const float* __restrict__ E, const int* __restrict__ offs,
                       const int* __restrict__ ccol, const float* __restrict__ cval,
                       float* __restrict__ front) {
    int r = blockIdx.x * (blockDim.x >> 6) + (threadIdx.x >> 6);
    int d = threadIdx.x & 63;
    if (r >= NTOT) return;
    int s = offs[r], e = offs[r + 1];
    float acc = E[(size_t)r * D + d];
    for (int p = s; p < e; ++p) {
        int   c = ccol[p];
        float v = cval[p];
        acc += v * E[(size_t)c * D + d];
    }
    front[(size_t)r * D + d] = acc;
}

// Per-row: fc = lrelu(front@Wf^T + bf); back = lrelu((E*front)@Wb^T + bb);
// E_new = fc + back (in place); inv[r] = 1/max(||E_new||, eps)
__global__ __launch_bounds__(256) void k_rowmv(
    const float* __restrict__ front, float* __restrict__ E,
    const float* __restrict__ Wf, const float* __restrict__ bfv,
    const float* __restrict__ Wb, const float* __restrict__ bbv,
    float* __restrict__ inv) {
    int r = blockIdx.x * blockDim.x + threadIdx.x;
    if (r >= NTOT) return;
    float f[D], g[D];
    const float* fp = front + (size_t)r * D;
    const float* ep = E + (size_t)r * D;
    #pragma unroll
    for (int q = 0; q < 16; q++) {
        float4 a = *(const float4*)(fp + q * 4);
        float4 b = *(const float4*)(ep + q * 4);
        f[q*4+0] = a.x; f[q*4+1] = a.y; f[q*4+2] = a.z; f[q*4+3] = a.w;
        g[q*4+0] = a.x*b.x; g[q*4+1] = a.y*b.y; g[q*4+2] = a.z*b.z; g[q*4+3] = a.w*b.w;
    }
    float nsq = 0.f;
    float* erow = E + (size_t)r * D;
    for (int j = 0; j < D; j++) {
        const float* wf = Wf + j * D;
        const float* wb = Wb + j * D;
        float aF0 = bfv[j], aF1 = 0.f, aB0 = bbv[j], aB1 = 0.f;
        #pragma unroll
        for (int k = 0; k < D; k += 2) {
            aF0 = fmaf(wf[k],     f[k],     aF0);
            aF1 = fmaf(wf[k + 1], f[k + 1], aF1);
            aB0 = fmaf(wb[k],     g[k],     aB0);
            aB1 = fmaf(wb[k + 1], g[k + 1], aB1);
        }
        float aF = aF0 + aF1, aB = aB0 + aB1;
        float vF = (aF > 0.f) ? aF : NEG * aF;
        float vB = (aB > 0.f) ? aB : NEG * aB;
        float en = vF + vB;
        erow[j] = en;
        nsq += en * en;
    }
    float nrm = fmaxf(sqrtf(nsq), 1e-12f);
    inv[r] = 1.0f / nrm;
}

__global__ void k_normout(const float* __restrict__ E, const float* __restrict__ inv,
                          float* __restrict__ out, int chunk) {
    int t = blockIdx.x * blockDim.x + threadIdx.x;
    if (t >= NTOT * 16) return;
    int r = t >> 4, q = t & 15;
    float s = inv[r];
    float4 v = *(const float4*)(E + (size_t)r * D + q * 4);
    float4 o;
    o.x = v.x * s; o.y = v.y * s; o.z = v.z * s; o.w = v.w * s;
    *(float4*)(out + (size_t)r * OUTD + (size_t)chunk * D + q * 4) = o;
}

extern "C" void kernel_launch(void* const* d_in, const int* in_sizes, int n_in,
                              void* d_out, int out_size, void* d_ws, size_t ws_size,
                              hipStream_t stream) {
    const float* ue   = (const float*)d_in[0];
    const float* ie   = (const float*)d_in[1];
    const int*   erow = (const int*)d_in[2];
    const int*   ecol = (const int*)d_in[3];
    const float* eval = (const float*)d_in[4];
    const float* Wf   = (const float*)d_in[5];
    const float* bfv  = (const float*)d_in[6];
    const float* Wb   = (const float*)d_in[7];
    const float* bbv  = (const float*)d_in[8];
    float* out = (float*)d_out;

    float* E     = (float*)d_ws;                    // NTOT*D
    float* front = E + (size_t)NTOT * D;            // NTOT*D
    float* invn  = front + (size_t)NTOT * D;        // NTOT
    int*   cnt   = (int*)(invn + NTOT);             // NTOT
    int*   offs  = cnt + NTOT;                      // NTOT+1
    int*   cur   = offs + NTOT + 1;                 // NTOT
    int*   part  = cur + NTOT;                      // 1024
    int*   ccol  = part + 1024;                     // NEDGE
    float* cval  = (float*)(ccol + NEDGE);          // NEDGE

    hipMemsetAsync(cnt, 0, NTOT * sizeof(int), stream);
    k_init<<<(NTOT * 16 + 255) / 256, 256, 0, stream>>>(ue, ie, E, out);
    k_hist<<<(NEDGE + 255) / 256, 256, 0, stream>>>(erow, cnt);
    k_scan_a<<<NBLK, 256, 0, stream>>>(cnt, part);
    k_scan_b<<<1, 1024, 0, stream>>>(part);
    k_scan_c<<<NBLK, 256, 0, stream>>>(cnt, part, offs, cur);
    k_scatter<<<(NEDGE + 255) / 256, 256, 0, stream>>>(erow, ecol, eval, cur, ccol, cval);

    for (int i = 0; i < 3; i++) {
        k_spmm<<<(NTOT + 3) / 4, 256, 0, stream>>>(E, offs, ccol, cval, front);
        k_rowmv<<<(NTOT + 255) / 256, 256, 0, stream>>>(
            front, E, Wf + (size_t)i * D * D, bfv + (size_t)i * D,
            Wb + (size_t)i * D * D, bbv + (size_t)i * D, invn);
        k_normout<<<(NTOT * 16 + 255) / 256, 256, 0, stream>>>(E, invn, out, i + 1);
    }
}

// Round 3
// 1240.136 us; speedup vs baseline: 1.3678x; 1.3678x over previous
//
#include <hip/hip_runtime.h>
#include <hip/hip_bf16.h>
#include <stdint.h>

#define N_USER 100000
#define N_ITEM 50000
#define NTOT   150000
#define NEDGE  1200000
#define D      64
#define OUTD   256
#define NEG    0.01f
#define NBLK   586   // ceil(150000/256)

// Build E = concat(user_emb, item_emb) and write output chunk 0 (raw emb, fp32)
__global__ void k_init(const float* __restrict__ ue, const float* __restrict__ ie,
                       float* __restrict__ E, float* __restrict__ out) {
    int t = blockIdx.x * blockDim.x + threadIdx.x;
    if (t >= NTOT * 16) return;
    int r = t >> 4, q = t & 15;
    const float* src = (r < N_USER) ? (ue + (size_t)r * D)
                                    : (ie + (size_t)(r - N_USER) * D);
    float4 v = *(const float4*)(src + q * 4);
    *(float4*)(E + (size_t)r * D + q * 4) = v;
    *(float4*)(out + (size_t)r * OUTD + q * 4) = v;
}

__global__ void k_hist(const int* __restrict__ row, int* __restrict__ cnt) {
    int e = blockIdx.x * blockDim.x + threadIdx.x;
    if (e < NEDGE) atomicAdd(&cnt[row[e]], 1);
}

// Phase A: per-block (256) partial sums of counts
__global__ void k_scan_a(const int* __restrict__ cnt, int* __restrict__ part) {
    __shared__ int s[4];
    int i = blockIdx.x * 256 + threadIdx.x;
    int v = (i < NTOT) ? cnt[i] : 0;
    for (int off = 32; off; off >>= 1) v += __shfl_down(v, off, 64);
    if ((threadIdx.x & 63) == 0) s[threadIdx.x >> 6] = v;
    __syncthreads();
    if (threadIdx.x == 0) part[blockIdx.x] = s[0] + s[1] + s[2] + s[3];
}

// Phase B: single-block exclusive scan of NBLK partials
__global__ void k_scan_b(int* __restrict__ part) {
    __shared__ int s[1024];
    int t = threadIdx.x;
    int v = (t < NBLK) ? part[t] : 0;
    s[t] = v;
    __syncthreads();
    for (int off = 1; off < 1024; off <<= 1) {
        int x = (t >= off) ? s[t - off] : 0;
        __syncthreads();
        s[t] += x;
        __syncthreads();
    }
    if (t < NBLK) part[t] = s[t] - v;  // exclusive
}

// Phase C: in-block exclusive scan + block base -> offsets and cursor copy
__global__ void k_scan_c(const int* __restrict__ cnt, const int* __restrict__ part,
                         int* __restrict__ offs, int* __restrict__ cur) {
    __shared__ int ws[4];
    int i = blockIdx.x * 256 + threadIdx.x;
    int v = (i < NTOT) ? cnt[i] : 0;
    int lane = threadIdx.x & 63, w = threadIdx.x >> 6;
    int x = v;
    for (int o = 1; o < 64; o <<= 1) {
        int y = __shfl_up(x, o, 64);
        if (lane >= o) x += y;
    }
    if (lane == 63) ws[w] = x;
    __syncthreads();
    int base = part[blockIdx.x];
    for (int k = 0; k < w; k++) base += ws[k];
    int excl = base + x - v;
    if (i < NTOT) { offs[i] = excl; cur[i] = excl; }
    if (i == 0) offs[NTOT] = NEDGE;
}

__global__ void k_scatter(const int* __restrict__ row, const int* __restrict__ col,
                          const float* __restrict__ val, int* __restrict__ cur,
                          int* __restrict__ ccol, float* __restrict__ cval) {
    int e = blockIdx.x * blockDim.x + threadIdx.x;
    if (e >= NEDGE) return;
    int r = row[e];
    int p = atomicAdd(&cur[r], 1);
    ccol[p] = col[e];
    cval[p] = val[e];
}

// front = (H + I) @ E : wave per row, lane per dim
__global__ void k_spmm(const float* __restrict__ E, const int* __restrict__ offs,
                       const int* __restrict__ ccol, const float* __restrict__ cval,
                       float* __restrict__ front) {
    int r = blockIdx.x * (blockDim.x >> 6) + (threadIdx.x >> 6);
    int d = threadIdx.x & 63;
    if (r >= NTOT) return;
    int s = offs[r], e = offs[r + 1];
    float acc = E[(size_t)r * D + d];
    for (int p = s; p < e; ++p) {
        int   c = ccol[p];
        float v = cval[p];
        acc += v * E[(size_t)c * D + d];
    }
    front[(size_t)r * D + d] = acc;
}

// Per-row: fc = lrelu(front@Wf^T + bf); back = lrelu((E*front)@Wb^T + bb);
// E_new = fc + back (in place, UNNORMALIZED for next layer);
// out chunk = E_new / max(||E_new||, eps).
// launch_bounds(256,2): VGPR cap 256 so f/g/o (192 regs) stay in registers.
// Round-2 lesson: default heuristic capped at 72 VGPR -> 575 MB/dispatch spill.
__global__ __launch_bounds__(256, 2) void k_rowmv(
    const float* __restrict__ front, float* __restrict__ E,
    const float* __restrict__ Wf, const float* __restrict__ bfv,
    const float* __restrict__ Wb, const float* __restrict__ bbv,
    float* __restrict__ out, int chunk) {
    int r = blockIdx.x * blockDim.x + threadIdx.x;
    if (r >= NTOT) return;
    float f[D], g[D], o[D];
    const float* fp = front + (size_t)r * D;
    const float* ep = E + (size_t)r * D;
    #pragma unroll
    for (int q = 0; q < 16; q++) {
        float4 a = *(const float4*)(fp + q * 4);
        float4 b = *(const float4*)(ep + q * 4);
        f[q*4+0] = a.x; f[q*4+1] = a.y; f[q*4+2] = a.z; f[q*4+3] = a.w;
        g[q*4+0] = a.x*b.x; g[q*4+1] = a.y*b.y; g[q*4+2] = a.z*b.z; g[q*4+3] = a.w*b.w;
    }
    float nsq = 0.f;
    for (int j = 0; j < D; j++) {
        const float* wf = Wf + j * D;
        const float* wb = Wb + j * D;
        float aF0 = bfv[j], aF1 = 0.f, aB0 = bbv[j], aB1 = 0.f;
        #pragma unroll
        for (int k = 0; k < D; k += 2) {
            aF0 = fmaf(wf[k],     f[k],     aF0);
            aF1 = fmaf(wf[k + 1], f[k + 1], aF1);
            aB0 = fmaf(wb[k],     g[k],     aB0);
            aB1 = fmaf(wb[k + 1], g[k + 1], aB1);
        }
        float aF = aF0 + aF1, aB = aB0 + aB1;
        float vF = (aF > 0.f) ? aF : NEG * aF;
        float vB = (aB > 0.f) ? aB : NEG * aB;
        float en = vF + vB;
        o[j] = en;
        nsq += en * en;
    }
    float inv = 1.0f / fmaxf(sqrtf(nsq), 1e-12f);
    float* erow = E + (size_t)r * D;
    float* orow = out + (size_t)r * OUTD + (size_t)chunk * D;
    #pragma unroll
    for (int q = 0; q < 16; q++) {
        float4 u;
        u.x = o[q*4+0]; u.y = o[q*4+1]; u.z = o[q*4+2]; u.w = o[q*4+3];
        *(float4*)(erow + q * 4) = u;
        float4 w;
        w.x = u.x * inv; w.y = u.y * inv; w.z = u.z * inv; w.w = u.w * inv;
        *(float4*)(orow + q * 4) = w;
    }
}

extern "C" void kernel_launch(void* const* d_in, const int* in_sizes, int n_in,
                              void* d_out, int out_size, void* d_ws, size_t ws_size,
                              hipStream_t stream) {
    const float* ue   = (const float*)d_in[0];
    const float* ie   = (const float*)d_in[1];
    const int*   erow = (const int*)d_in[2];
    const int*   ecol = (const int*)d_in[3];
    const float* eval = (const float*)d_in[4];
    const float* Wf   = (const float*)d_in[5];
    const float* bfv  = (const float*)d_in[6];
    const float* Wb   = (const float*)d_in[7];
    const float* bbv  = (const float*)d_in[8];
    float* out = (float*)d_out;

    float* E     = (float*)d_ws;                    // NTOT*D
    float* front = E + (size_t)NTOT * D;            // NTOT*D
    float* invn  = front + (size_t)NTOT * D;        // NTOT (unused now, kept for layout)
    int*   cnt   = (int*)(invn + NTOT);             // NTOT
    int*   offs  = cnt + NTOT;                      // NTOT+1
    int*   cur   = offs + NTOT + 1;                 // NTOT
    int*   part  = cur + NTOT;                      // 1024
    int*   ccol  = part + 1024;                     // NEDGE
    float* cval  = (float*)(ccol + NEDGE);          // NEDGE

    hipMemsetAsync(cnt, 0, NTOT * sizeof(int), stream);
    k_init<<<(NTOT * 16 + 255) / 256, 256, 0, stream>>>(ue, ie, E, out);
    k_hist<<<(NEDGE + 255) / 256, 256, 0, stream>>>(erow, cnt);
    k_scan_a<<<NBLK, 256, 0, stream>>>(cnt, part);
    k_scan_b<<<1, 1024, 0, stream>>>(part);
    k_scan_c<<<NBLK, 256, 0, stream>>>(cnt, part, offs, cur);
    k_scatter<<<(NEDGE + 255) / 256, 256, 0, stream>>>(erow, ecol, eval, cur, ccol, cval);

    for (int i = 0; i < 3; i++) {
        k_spmm<<<(NTOT + 3) / 4, 256, 0, stream>>>(E, offs, ccol, cval, front);
        k_rowmv<<<(NTOT + 255) / 256, 256, 0, stream>>>(
            front, E, Wf + (size_t)i * D * D, bfv + (size_t)i * D,
            Wb + (size_t)i * D * D, bbv + (size_t)i * D, out, i + 1);
    }
}